// Round 4
// baseline (178.410 us; speedup 1.0000x reference)
//
#include <hip/hip_runtime.h>
#include <cstdint>
#include <cstddef>

// LocallyDirected1D: y[b,o] = tanh( sum_{e: out_idx[e]==o} x[b, in_idx[e]] * w[e] + bias[o] )
// out_idx sorted ascending; in_idx == arange in practice (verified per window; wave-uniform
// clamped-gather fallback otherwise).
//
// R4: single fused main kernel, exactly-once non-atomic output writes.
//  K1 ld1d_bounds: bnd[o] = lower_bound(out_idx, o) via linear transition scan (d_ws).
//  K2 ld1d_fused : block owns OPB=16 consecutive outputs (=> contiguous edge range).
//    Wave sweeps the range in 256-edge windows for 4 rows at a time (4 sweeps x 4 rows
//    = 16 rows per wave; 4 waves = 64 rows). Per window: run-structure masks computed
//    once (row-independent), 4 coalesced float4 x-loads issued up front, DPP masked
//    segmented scan per row. Runs ending inside the window are emitted (tanh+bias fused)
//    by exactly one lane; the window-trailing run becomes a wave-uniform per-row carry,
//    flushed when a later window opens with a different first output (or at the end).
//    Empty outputs are written from the precomputed boundaries. No LDS tiles, no atomics.

constexpr int OPB = 16;    // outputs per block
constexpr int RPG = 4;     // rows per group (one sweep)
constexpr int NGR = 4;     // groups per wave
constexpr int WPB = 4;     // waves per block  (WPB*NGR*RPG = 64 rows)

#define DPP_SHR1 0x111
#define DPP_SHR2 0x112
#define DPP_SHR4 0x114
#define DPP_SHR8 0x118
#define DPP_BC15 0x142
#define DPP_BC31 0x143

// s += mask * dpp_shift(s); bound_ctrl=true -> invalid source reads 0.
#define SCAN_STEP(S, MF, CTRL, RM)                                                            \
    {                                                                                         \
        int _t = __builtin_amdgcn_update_dpp(0, __float_as_int(S), (CTRL), (RM), 0xF, true);  \
        (S) = fmaf((MF), __int_as_float(_t), (S));                                            \
    }

#define MAXS_STEP(R, CTRL, RM)                                                                \
    {                                                                                         \
        int _t = __builtin_amdgcn_update_dpp(0, (R), (CTRL), (RM), 0xF, true);                \
        (R) = max((R), _t);                                                                   \
    }

// K1: bnd[o] = first e with out_idx[e] >= o, for o in [0, n_out].  Exactly-once writes.
__global__ __launch_bounds__(256)
void ld1d_bounds(const int* __restrict__ out_idx, int* __restrict__ bnd,
                 int nnz, int n_out)
{
    int e = blockIdx.x * 256 + threadIdx.x;
    if (e >= nnz) return;
    int cur  = out_idx[e];
    int prev = (e == 0) ? -1 : out_idx[e - 1];
    for (int o = prev + 1; o <= cur; ++o) bnd[o] = e;     // e==0 fills [0, cur]
    if (e == nnz - 1)
        for (int o = cur + 1; o <= n_out; ++o) bnd[o] = nnz;
}

__global__ __launch_bounds__(256)
void ld1d_fused(const float* __restrict__ x, const float* __restrict__ wgt,
                const float* __restrict__ bias, const int* __restrict__ in_idx,
                const int* __restrict__ out_idx, const int* __restrict__ bnd,
                float* __restrict__ out,
                int n_in, int nnz, int n_out, int batch)
{
    __shared__ int sbO[OPB + 1];
    const int tid  = threadIdx.x;
    const int lane = tid & 63;
    const int wv   = tid >> 6;
    const int O0   = blockIdx.x * OPB;
    const int nO   = min(OPB, n_out - O0);

    if (tid <= nO) sbO[tid] = bnd[min(O0 + tid, n_out)];
    __syncthreads();

    const int E0 = sbO[0];
    const int E1 = sbO[nO];
    const int CB = E0 & ~3;
    const int CE = (E1 + 3) & ~3;

    const int b0w = wv * (NGR * RPG);

// Per-row window body. Wave-uniform guard outside; all cross-lane ops unconditional.
#define ROWC(XV, CY, J)                                                                       \
    {                                                                                         \
        float q0 = (XV).x * wq.x, q1 = (XV).y * wq.y, q2 = (XV).z * wq.z, q3 = (XV).w * wq.w; \
        float s = q3; s = fmaf(tm2, q2, s); s = fmaf(tm1, q1, s); s = fmaf(tm0, q0, s);       \
        SCAN_STEP(s, mf1,  DPP_SHR1, 0xF);                                                    \
        SCAN_STEP(s, mf2,  DPP_SHR2, 0xF);                                                    \
        SCAN_STEP(s, mf4,  DPP_SHR4, 0xF);                                                    \
        SCAN_STEP(s, mf8,  DPP_SHR8, 0xF);                                                    \
        SCAN_STEP(s, mf15, DPP_BC15, 0xA);                                                    \
        SCAN_STEP(s, mf31, DPP_BC31, 0xC);                                                    \
        const float sp = __shfl_up(s, 1);                                                     \
        if (EendT) {                                                                          \
            const int o = ov.w;                                                               \
            if ((unsigned)(o - O0) < (unsigned)nO) {                                          \
                float v = s + ((o == firsto) ? (CY) : 0.f);                                   \
                out[(size_t)(b0 + (J)) * n_out + o] = tanhf(v + bias[o]);                     \
            }                                                                                 \
        }                                                                                     \
        if (hasB) {                                                                           \
            const int o = ov.x;                                                               \
            if ((unsigned)(o - O0) < (unsigned)nO) {                                          \
                float v = q0; v = fmaf(hm1, q1, v); v = fmaf(hm2, q2, v);                     \
                v = fmaf(hm3, q3, v);                                                         \
                if (cont) v += sp;                                                            \
                if (o == firsto) v += (CY);                                                   \
                out[(size_t)(b0 + (J)) * n_out + o] = tanhf(v + bias[o]);                     \
            }                                                                                 \
        }                                                                                     \
        if (hasM1) {                                                                          \
            const int o = ov.y;                                                               \
            if ((unsigned)(o - O0) < (unsigned)nO)                                            \
                out[(size_t)(b0 + (J)) * n_out + o] = tanhf(fmaf(mw, q2, q1) + bias[o]);      \
        }                                                                                     \
        if (hasM2) {                                                                          \
            const int o = ov.z;                                                               \
            if ((unsigned)(o - O0) < (unsigned)nO)                                            \
                out[(size_t)(b0 + (J)) * n_out + o] = tanhf(q2 + bias[o]);                    \
        }                                                                                     \
        (CY) = __int_as_float(__builtin_amdgcn_readlane(__float_as_int(s), 63)) +             \
               (single ? (CY) : 0.f);                                                         \
    }

#define FLUSH_ROW(CY, J)                                                                      \
    if (b0 + (J) < batch) out[(size_t)(b0 + (J)) * n_out + pend] = tanhf((CY) + bo);

    for (int g = 0; g < NGR; ++g) {
        const int b0 = b0w + g * RPG;
        if (b0 >= batch) break;
        float cy0 = 0.f, cy1 = 0.f, cy2 = 0.f, cy3 = 0.f;
        int pend = -1;

        for (int c0 = CB; c0 < CE; c0 += 256) {
            const int e0 = c0 + lane * 4;

            int4 iv; int4 ov; float4 wq; bool fok;
            if (e0 + 3 < nnz) {
                iv = *reinterpret_cast<const int4*>(in_idx + e0);
                ov = *reinterpret_cast<const int4*>(out_idx + e0);
                wq = *reinterpret_cast<const float4*>(wgt + e0);
                fok = (iv.x == e0) && (iv.y == e0 + 1) && (iv.z == e0 + 2) && (iv.w == e0 + 3);
            } else if (e0 < nnz) {
                const int last = nnz - 1;
                int a0 = min(e0, last), a1 = min(e0 + 1, last),
                    a2 = min(e0 + 2, last), a3 = min(e0 + 3, last);
                iv = make_int4(in_idx[a0], in_idx[a1], in_idx[a2], in_idx[a3]);
                ov = make_int4(out_idx[a0], out_idx[a1], out_idx[a2], out_idx[a3]);
                wq = make_float4(wgt[a0],
                                 e0 + 1 < nnz ? wgt[a1] : 0.f,
                                 e0 + 2 < nnz ? wgt[a2] : 0.f,
                                 e0 + 3 < nnz ? wgt[a3] : 0.f);
                fok = false;
            } else {
                const int o = out_idx[nnz - 1];
                iv = make_int4(0, 0, 0, 0);
                ov = make_int4(o, o, o, o);
                wq = make_float4(0.f, 0.f, 0.f, 0.f);
                fok = true;
            }
            const bool fast = (bool)__all((int)fok);
            const int nmax = n_in - 1;
            const int ix0 = min(max(iv.x, 0), nmax), ix1 = min(max(iv.y, 0), nmax);
            const int ix2 = min(max(iv.z, 0), nmax), ix3 = min(max(iv.w, 0), nmax);
            const int xb4 = (e0 + 3 < nnz) ? e0 : 0;    // fast-path base (w=0 for pads)

            // Run structure (row-independent).
            const bool b01 = ov.x != ov.y, b12 = ov.y != ov.z, b23 = ov.z != ov.w;
            const bool hasB = b01 || b12 || b23;
            const int  pw   = __shfl_up(ov.w, 1);
            const bool cont = (lane > 0) && (ov.x == pw);
            const int  cnx  = __shfl_down((int)cont, 1);
            const bool EendT = (lane < 63) && !cnx;     // tail run ends at my e3
            const bool fbrk = hasB || !cont;

            const float tm2 = b23 ? 0.f : 1.f;
            const float tm1 = (b23 || b12) ? 0.f : 1.f;
            const float tm0 = (b23 || b12 || b01) ? 0.f : 1.f;
            const float hm1 = b01 ? 0.f : 1.f;
            const float hm2 = (b01 || b12) ? 0.f : 1.f;
            const float hm3 = (b01 || b12 || b23) ? 0.f : 1.f;
            const bool  hasM1 = b01 && (b12 || b23);
            const bool  hasM2 = b12 && b23;
            const float mw    = b12 ? 0.f : 1.f;

            int r = fbrk ? lane : 0;
            MAXS_STEP(r, DPP_SHR1, 0xF); MAXS_STEP(r, DPP_SHR2, 0xF);
            MAXS_STEP(r, DPP_SHR4, 0xF); MAXS_STEP(r, DPP_SHR8, 0xF);
            MAXS_STEP(r, DPP_BC15, 0xA); MAXS_STEP(r, DPP_BC31, 0xC);

            const float mf1  = (r <= lane - 1) ? 1.f : 0.f;
            const float mf2  = (r <= lane - 2) ? 1.f : 0.f;
            const float mf4  = (r <= lane - 4) ? 1.f : 0.f;
            const float mf8  = (r <= lane - 8) ? 1.f : 0.f;
            const float mf15 = (r <= (lane & ~15) - 1) ? 1.f : 0.f;
            const float mf31 = (r <= 31) ? 1.f : 0.f;

            const int firsto = __builtin_amdgcn_readlane(ov.x, 0);
            const int lasto  = __builtin_amdgcn_readlane(ov.w, 63);
            const bool single = (firsto == lasto);

            // Flush pending carry if its run closed exactly at the window boundary.
            if (pend >= 0 && pend != firsto) {
                if ((unsigned)(pend - O0) < (unsigned)nO && lane == 0) {
                    const float bo = bias[pend];
                    FLUSH_ROW(cy0, 0) FLUSH_ROW(cy1, 1) FLUSH_ROW(cy2, 2) FLUSH_ROW(cy3, 3)
                }
                cy0 = cy1 = cy2 = cy3 = 0.f;
            }

            // x loads for the 4 rows, issued together.
            const float* xr0 = x + (size_t)min(b0 + 0, batch - 1) * (size_t)n_in;
            const float* xr1 = x + (size_t)min(b0 + 1, batch - 1) * (size_t)n_in;
            const float* xr2 = x + (size_t)min(b0 + 2, batch - 1) * (size_t)n_in;
            const float* xr3 = x + (size_t)min(b0 + 3, batch - 1) * (size_t)n_in;
            float4 xv0, xv1, xv2, xv3;
            if (fast) {
                xv0 = *reinterpret_cast<const float4*>(xr0 + xb4);
                xv1 = *reinterpret_cast<const float4*>(xr1 + xb4);
                xv2 = *reinterpret_cast<const float4*>(xr2 + xb4);
                xv3 = *reinterpret_cast<const float4*>(xr3 + xb4);
            } else {
                xv0 = make_float4(xr0[ix0], xr0[ix1], xr0[ix2], xr0[ix3]);
                xv1 = make_float4(xr1[ix0], xr1[ix1], xr1[ix2], xr1[ix3]);
                xv2 = make_float4(xr2[ix0], xr2[ix1], xr2[ix2], xr2[ix3]);
                xv3 = make_float4(xr3[ix0], xr3[ix1], xr3[ix2], xr3[ix3]);
            }

            ROWC(xv0, cy0, 0)
            ROWC(xv1, cy1, 1)
            ROWC(xv2, cy2, 2)
            ROWC(xv3, cy3, 3)

            pend = lasto;
        }

        // Final flush of the trailing run.
        if (pend >= 0 && (unsigned)(pend - O0) < (unsigned)nO && lane == 0) {
            const float bo = bias[pend];
            FLUSH_ROW(cy0, 0) FLUSH_ROW(cy1, 1) FLUSH_ROW(cy2, 2) FLUSH_ROW(cy3, 3)
        }
    }

    // Outputs with zero edges: y = tanh(bias). Each wave writes its 16 rows.
    for (int k = 0; k < nO; ++k) {
        if (sbO[k] == sbO[k + 1]) {
            const int o = O0 + k;
            const float v = tanhf(bias[o]);
            const int b = b0w + lane;
            if (lane < NGR * RPG && b < batch)
                out[(size_t)b * n_out + o] = v;
        }
    }
#undef ROWC
#undef FLUSH_ROW
}

extern "C" void kernel_launch(void* const* d_in, const int* in_sizes, int n_in_arrs,
                              void* d_out, int out_size, void* d_ws, size_t ws_size,
                              hipStream_t stream)
{
    const float* x       = (const float*)d_in[0];
    const float* wgt     = (const float*)d_in[1];
    const float* bias    = (const float*)d_in[2];
    const int*   in_idx  = (const int*)d_in[3];
    const int*   out_idx = (const int*)d_in[4];
    float*       out     = (float*)d_out;
    int*         bnd     = (int*)d_ws;                 // (n_out+1) ints

    const int nnz   = in_sizes[1];
    const int n_out = in_sizes[2];           // N_OUT * FILTERS(=1)
    const int batch = out_size / n_out;      // 64
    const int n_in  = in_sizes[0] / batch;   // 1,000,000

    hipLaunchKernelGGL(ld1d_bounds, dim3((nnz + 255) / 256), dim3(256), 0, stream,
                       out_idx, bnd, nnz, n_out);

    const int blocks = (n_out + OPB - 1) / OPB;
    hipLaunchKernelGGL(ld1d_fused, dim3(blocks), dim3(256), 0, stream,
                       x, wgt, bias, in_idx, out_idx, bnd, out,
                       n_in, nnz, n_out, batch);
}

// Round 5
// 60.534 us; speedup vs baseline: 2.9472x; 2.9472x over previous
//
#include <hip/hip_runtime.h>
#include <cstdint>
#include <cstddef>

// LocallyDirected1D: y[b,o] = tanh( sum_{e: out_idx[e]==o} x[b, in_idx[e]] * w[e] + bias[o] )
// out_idx sorted ascending; in_idx == arange in practice (verified per window; wave-uniform
// clamped-gather fallback otherwise).
//
// R5 = R3 structure (zero / accum / finish) with:
//  * EPW=512: each lane owns 8 contiguous edges. In-lane run sums via two 7-fma chains:
//      t_j (suffix, stops at first break after j)  -> head run t_0, mid runs t_j
//      s_j (prefix, restarts after each break)     -> tail-run input s_7 for the wave scan
//    Wave-level masked Hillis-Steele DPP scan (6 steps) identical to R3.
//  * Register double-buffered prefetch: next 2-row batch's x loads issued before
//    processing the current batch.
//  Emissions via fp32 agent-scope atomics into pre (=d_out, zeroed by K0); exactly as R3
//  (split emissions across windows/lanes sum correctly). K2 applies bias+tanh in place.

constexpr int EPW = 512;   // edges per window (8 per lane)
constexpr int RPW = 16;    // batch rows per wave (4 waves share a window)
constexpr int WPB = 4;     // waves per block

#define DPP_SHR1 0x111
#define DPP_SHR2 0x112
#define DPP_SHR4 0x114
#define DPP_SHR8 0x118
#define DPP_BC15 0x142
#define DPP_BC31 0x143

#define SCAN_STEP(S, MF, CTRL, RM)                                                            \
    {                                                                                         \
        int _t = __builtin_amdgcn_update_dpp(0, __float_as_int(S), (CTRL), (RM), 0xF, true);  \
        (S) = fmaf((MF), __int_as_float(_t), (S));                                            \
    }

#define MAXS_STEP(R, CTRL, RM)                                                                \
    {                                                                                         \
        int _t = __builtin_amdgcn_update_dpp(0, (R), (CTRL), (RM), 0xF, true);                \
        (R) = max((R), _t);                                                                   \
    }

__device__ __forceinline__ void atomAddF(float* p, float v) {
    __hip_atomic_fetch_add(p, v, __ATOMIC_RELAXED, __HIP_MEMORY_SCOPE_AGENT);
}

__global__ __launch_bounds__(256)
void ld1d_zero(float* __restrict__ p, int n4, int ntot)
{
    int i = blockIdx.x * 256 + threadIdx.x;
    if (i < n4)
        *reinterpret_cast<float4*>(p + (size_t)i * 4) = make_float4(0.f, 0.f, 0.f, 0.f);
    if (blockIdx.x == 0 && threadIdx.x == 0)
        for (int k = n4 * 4; k < ntot; ++k) p[k] = 0.f;
}

__global__ __launch_bounds__(256)
void ld1d_accum(const float* __restrict__ x, const float* __restrict__ wgt,
                const int* __restrict__ in_idx, const int* __restrict__ out_idx,
                float* __restrict__ pre, int n_in, int nnz, int n_out, int batch, int wpw)
{
    const int lane = threadIdx.x & 63;
    const int gw   = blockIdx.x * WPB + (threadIdx.x >> 6);
    const int wid  = gw / wpw;
    const long long c0l = (long long)wid * EPW;
    if (c0l >= (long long)nnz) return;
    const int b0 = (gw - wid * wpw) * RPW;
    const int nrows = min(RPW, batch - b0);
    if (nrows <= 0) return;

    const int e0   = (int)c0l + lane * 8;
    const int last = nnz - 1;

    int   iv[8]; int ov[8]; float w[8];
    bool fok;
    if (e0 + 7 < nnz) {
        int4 i0 = *reinterpret_cast<const int4*>(in_idx + e0);
        int4 i1 = *reinterpret_cast<const int4*>(in_idx + e0 + 4);
        int4 o0 = *reinterpret_cast<const int4*>(out_idx + e0);
        int4 o1 = *reinterpret_cast<const int4*>(out_idx + e0 + 4);
        float4 w0 = *reinterpret_cast<const float4*>(wgt + e0);
        float4 w1 = *reinterpret_cast<const float4*>(wgt + e0 + 4);
        iv[0]=i0.x; iv[1]=i0.y; iv[2]=i0.z; iv[3]=i0.w; iv[4]=i1.x; iv[5]=i1.y; iv[6]=i1.z; iv[7]=i1.w;
        ov[0]=o0.x; ov[1]=o0.y; ov[2]=o0.z; ov[3]=o0.w; ov[4]=o1.x; ov[5]=o1.y; ov[6]=o1.z; ov[7]=o1.w;
        w[0]=w0.x; w[1]=w0.y; w[2]=w0.z; w[3]=w0.w; w[4]=w1.x; w[5]=w1.y; w[6]=w1.z; w[7]=w1.w;
        fok = true;
        #pragma unroll
        for (int k = 0; k < 8; ++k) fok = fok && (iv[k] == e0 + k);
    } else if (e0 < nnz) {
        #pragma unroll
        for (int k = 0; k < 8; ++k) {
            int a = min(e0 + k, last);
            iv[k] = in_idx[a]; ov[k] = out_idx[a];
            w[k]  = (e0 + k < nnz) ? wgt[a] : 0.f;
        }
        fok = false;
    } else {
        int o = out_idx[last];
        #pragma unroll
        for (int k = 0; k < 8; ++k) { iv[k] = 0; ov[k] = o; w[k] = 0.f; }
        fok = true;
    }
    const bool fast = (bool)__all((int)fok);

    // In-lane run structure (row-independent).
    bool bb[7]; float u[7];
    #pragma unroll
    for (int k = 0; k < 7; ++k) { bb[k] = (ov[k] != ov[k + 1]); u[k] = bb[k] ? 0.f : 1.f; }
    const bool hasB = bb[0] | bb[1] | bb[2] | bb[3] | bb[4] | bb[5] | bb[6];

    const int  pw   = __shfl_up(ov[7], 1);
    const bool cont = (lane > 0) && (ov[0] == pw);
    const bool fbrk = hasB || !cont;
    const int  fnext = __shfl_down((int)fbrk, 1);
    const bool Eend  = (lane == 63) || (fnext != 0);

    // Mid-run flags: run starts at j (bb[j-1]) and ends before e7 (a break in [j,6]).
    bool sfx[7];                       // sfx[j] = bb[j] | ... | bb[6]
    sfx[6] = bb[6];
    #pragma unroll
    for (int j = 5; j >= 1; --j) sfx[j] = bb[j] | sfx[j + 1];
    bool E[7];
    #pragma unroll
    for (int j = 1; j <= 6; ++j) E[j] = bb[j - 1] && sfx[j];
    const bool anyMid = (bool)__any((int)(E[1] | E[2] | E[3] | E[4] | E[5] | E[6]));

    // Run-start lane r -> per-step scan masks (identical to R3).
    int r = fbrk ? lane : 0;
    MAXS_STEP(r, DPP_SHR1, 0xF); MAXS_STEP(r, DPP_SHR2, 0xF);
    MAXS_STEP(r, DPP_SHR4, 0xF); MAXS_STEP(r, DPP_SHR8, 0xF);
    MAXS_STEP(r, DPP_BC15, 0xA); MAXS_STEP(r, DPP_BC31, 0xC);
    const float mf1  = (r <= lane - 1) ? 1.f : 0.f;
    const float mf2  = (r <= lane - 2) ? 1.f : 0.f;
    const float mf4  = (r <= lane - 4) ? 1.f : 0.f;
    const float mf8  = (r <= lane - 8) ? 1.f : 0.f;
    const float mf15 = (r <= (lane & ~15) - 1) ? 1.f : 0.f;
    const float mf31 = (r <= 31) ? 1.f : 0.f;

    // Clamped gather indices (slow path).
    const int nmax = n_in - 1;
    int ix[8];
    #pragma unroll
    for (int k = 0; k < 8; ++k) ix[k] = min(max(iv[k], 0), nmax);

    float* pb = pre + (size_t)b0 * (size_t)n_out;

    auto processRow = [&](const float q[8], float* pbr) {
        // suffix chains: t[j] = run sum starting at j (stops at first break)
        float t7 = q[7];
        float t6 = fmaf(u[6], t7, q[6]);
        float t5 = fmaf(u[5], t6, q[5]);
        float t4 = fmaf(u[4], t5, q[4]);
        float t3 = fmaf(u[3], t4, q[3]);
        float t2 = fmaf(u[2], t3, q[2]);
        float t1 = fmaf(u[1], t2, q[1]);
        float t0 = fmaf(u[0], t1, q[0]);
        // prefix chain: s7 = tail-run in-lane sum
        float s = q[0];
        s = fmaf(u[0], s, q[1]); s = fmaf(u[1], s, q[2]); s = fmaf(u[2], s, q[3]);
        s = fmaf(u[3], s, q[4]); s = fmaf(u[4], s, q[5]); s = fmaf(u[5], s, q[6]);
        s = fmaf(u[6], s, q[7]);
        // wave scan over tail sums
        SCAN_STEP(s, mf1,  DPP_SHR1, 0xF);
        SCAN_STEP(s, mf2,  DPP_SHR2, 0xF);
        SCAN_STEP(s, mf4,  DPP_SHR4, 0xF);
        SCAN_STEP(s, mf8,  DPP_SHR8, 0xF);
        SCAN_STEP(s, mf15, DPP_BC15, 0xA);
        SCAN_STEP(s, mf31, DPP_BC31, 0xC);
        if (Eend) atomAddF(pbr + ov[7], s);
        if (hasB) atomAddF(pbr + ov[0], t0);
        if (anyMid) {
            if (E[1]) atomAddF(pbr + ov[1], t1);
            if (E[2]) atomAddF(pbr + ov[2], t2);
            if (E[3]) atomAddF(pbr + ov[3], t3);
            if (E[4]) atomAddF(pbr + ov[4], t4);
            if (E[5]) atomAddF(pbr + ov[5], t5);
            if (E[6]) atomAddF(pbr + ov[6], t6);
        }
    };

    if (fast) {
        const float*  xb = x + (size_t)b0 * (size_t)n_in + e0;
        const size_t  rs = (size_t)n_in;
        const int nb2 = nrows >> 1;
        float4 ca0, ca1, cb0, cb1;
        if (nb2 > 0) {
            ca0 = *reinterpret_cast<const float4*>(xb);
            ca1 = *reinterpret_cast<const float4*>(xb + 4);
            cb0 = *reinterpret_cast<const float4*>(xb + rs);
            cb1 = *reinterpret_cast<const float4*>(xb + rs + 4);
        }
        for (int ib = 0; ib < nb2; ++ib) {
            float4 na0, na1, nb0, nb1;
            const bool more = (2 * ib + 2) < (nb2 << 1);
            if (more) {
                const float* nx = xb + (size_t)(2 * ib + 2) * rs;
                na0 = *reinterpret_cast<const float4*>(nx);
                na1 = *reinterpret_cast<const float4*>(nx + 4);
                nb0 = *reinterpret_cast<const float4*>(nx + rs);
                nb1 = *reinterpret_cast<const float4*>(nx + rs + 4);
            }
            {
                float q[8] = { ca0.x * w[0], ca0.y * w[1], ca0.z * w[2], ca0.w * w[3],
                               ca1.x * w[4], ca1.y * w[5], ca1.z * w[6], ca1.w * w[7] };
                processRow(q, pb);
            }
            {
                float q[8] = { cb0.x * w[0], cb0.y * w[1], cb0.z * w[2], cb0.w * w[3],
                               cb1.x * w[4], cb1.y * w[5], cb1.z * w[6], cb1.w * w[7] };
                processRow(q, pb + n_out);
            }
            pb += 2 * (size_t)n_out;
            if (more) { ca0 = na0; ca1 = na1; cb0 = nb0; cb1 = nb1; }
        }
        if (nrows & 1) {
            const float* nx = xb + (size_t)(nrows - 1) * rs;
            float4 a0 = *reinterpret_cast<const float4*>(nx);
            float4 a1 = *reinterpret_cast<const float4*>(nx + 4);
            float q[8] = { a0.x * w[0], a0.y * w[1], a0.z * w[2], a0.w * w[3],
                           a1.x * w[4], a1.y * w[5], a1.z * w[6], a1.w * w[7] };
            processRow(q, pb);
        }
    } else {
        const float* xr = x + (size_t)b0 * (size_t)n_in;
        for (int i = 0; i < nrows; ++i) {
            float q[8];
            #pragma unroll
            for (int k = 0; k < 8; ++k) q[k] = xr[ix[k]] * w[k];
            processRow(q, pb);
            xr += (size_t)n_in; pb += (size_t)n_out;
        }
    }
}

__global__ __launch_bounds__(256)
void ld1d_finish_vec(float* __restrict__ out, const float* __restrict__ bias, int n_out4)
{
    const int o4 = blockIdx.x * 256 + threadIdx.x;
    if (o4 >= n_out4) return;
    const size_t flat = (size_t)blockIdx.y * (size_t)n_out4 * 4 + (size_t)o4 * 4;
    float4 v  = *reinterpret_cast<float4*>(out + flat);
    float4 bz = *reinterpret_cast<const float4*>(bias + (size_t)o4 * 4);
    v.x = tanhf(v.x + bz.x); v.y = tanhf(v.y + bz.y);
    v.z = tanhf(v.z + bz.z); v.w = tanhf(v.w + bz.w);
    *reinterpret_cast<float4*>(out + flat) = v;
}

__global__ __launch_bounds__(256)
void ld1d_finish_scalar(float* __restrict__ out, const float* __restrict__ bias,
                        int n_out, int ntot)
{
    int i = blockIdx.x * 256 + threadIdx.x;
    if (i >= ntot) return;
    int o = i % n_out;
    out[i] = tanhf(out[i] + bias[o]);
}

extern "C" void kernel_launch(void* const* d_in, const int* in_sizes, int n_in_arrs,
                              void* d_out, int out_size, void* d_ws, size_t ws_size,
                              hipStream_t stream)
{
    const float* x       = (const float*)d_in[0];
    const float* wgt     = (const float*)d_in[1];
    const float* bias    = (const float*)d_in[2];
    const int*   in_idx  = (const int*)d_in[3];
    const int*   out_idx = (const int*)d_in[4];
    float*       out     = (float*)d_out;

    const int nnz   = in_sizes[1];
    const int n_out = in_sizes[2];           // N_OUT * FILTERS(=1)
    const int batch = out_size / n_out;      // 64
    const int n_in  = in_sizes[0] / batch;   // 1,000,000

    // K0: zero the accumulator (= d_out)
    const int n4 = out_size / 4;
    hipLaunchKernelGGL(ld1d_zero, dim3((n4 + 255) / 256), dim3(256), 0, stream,
                       out, n4, out_size);

    // K1: 512-edge windows, DPP segmented scan, atomic emissions
    const int nwin = (nnz + EPW - 1) / EPW;
    const int wpw  = (batch + RPW - 1) / RPW;            // waves per window
    const long long totalWaves = (long long)nwin * wpw;
    const int ablocks = (int)((totalWaves + WPB - 1) / WPB);
    hipLaunchKernelGGL(ld1d_accum, dim3(ablocks), dim3(256), 0, stream,
                       x, wgt, in_idx, out_idx, out, n_in, nnz, n_out, batch, wpw);

    // K2: bias + tanh in place
    if ((n_out & 3) == 0) {
        const int n_out4 = n_out / 4;
        hipLaunchKernelGGL(ld1d_finish_vec,
                           dim3((n_out4 + 255) / 256, batch), dim3(256), 0, stream,
                           out, bias, n_out4);
    } else {
        hipLaunchKernelGGL(ld1d_finish_scalar,
                           dim3((out_size + 255) / 256), dim3(256), 0, stream,
                           out, bias, n_out, out_size);
    }
}